// Round 6
// baseline (231.002 us; speedup 1.0000x reference)
//
#include <hip/hip_runtime.h>

// SSIM loss — fused separable-conv tile kernel, v6.
// vs v5: input staging LDS removed — h-pass loads its 20-float window per
// image directly from global (L1/L2 absorbs the 1.9x halo redundancy).
// Removes: stage loop, one barrier, 15.5KB LDS, h-pass LDS reads.
// LDS 39.4K -> 23.6K -> 6 blocks/CU (was 4): latency hiding was the v5
// bottleneck (VALUBusy 49%, occ 32%). Packed (s,d) v_pk_fma math kept.

typedef float v2f __attribute__((ext_vector_type(2)));
typedef float float4u __attribute__((ext_vector_type(4), aligned(4)));

#define IMG   512
#define NIMG  48
#define TW    32
#define TH    32
#define PH    42          // TH + 10
#define HSTR  46          // sh2 col stride in v2f units (368B)
#define TILES 16
#define NBLOCKS (NIMG * TILES * TILES)  // 12288

// exp(-(k-5)^2/4.5), unnormalized, symmetric.
#define G0 0.0038659204f
#define G1 0.0285655010f
#define G2 0.1353352832f
#define G3 0.4111123050f
#define G4 0.8007374029f
#define G5 1.0f

__global__ __launch_bounds__(256, 6) void ssim_tile_kernel(
    const float* __restrict__ img1, const float* __restrict__ img2,
    float* __restrict__ partials)
{
    __shared__ v2f sh2[2][TW][HSTR];     // [mu|x][col][row] (s,d) pairs, 23552 B
    __shared__ float s_part[4];

    const float gw[11] = {G0,G1,G2,G3,G4,G5,G4,G3,G2,G1,G0};

    const int tid = threadIdx.x;
    const int tx0 = blockIdx.x * TW - 5;
    const int ty0 = blockIdx.y * TH - 5;
    const float* __restrict__ p1 = img1 + (size_t)blockIdx.z * (IMG * IMG);
    const float* __restrict__ p2 = img2 + (size_t)blockIdx.z * (IMG * IMG);

    // h-pass task: 168 active threads, each = (row 0..41) x (8-col group 0..3)
    const bool hact = tid < 168;
    const int  hr  = hact ? (tid % 42) : 0;
    const int  hc0 = hact ? ((tid / 42) * 8) : 0;

    // ================= h-pass: global -> packed window -> conv =================
    if (hact) {
        v2f v[20];
        {
            const int gr  = ty0 + hr;
            const int gc0 = tx0 + hc0;
            const bool interior = (blockIdx.x >= 1) && (blockIdx.x <= TILES - 2) &&
                                  (blockIdx.y >= 1) && (blockIdx.y <= TILES - 2);
            if (interior) {
                const float* r1 = p1 + gr * IMG + gc0;
                const float* r2 = p2 + gr * IMG + gc0;
#pragma unroll
                for (int q = 0; q < 5; ++q) {
                    float4u A = *(const float4u*)&r1[4 * q];
                    float4u B = *(const float4u*)&r2[4 * q];
#pragma unroll
                    for (int j = 0; j < 4; ++j)
                        v[4 * q + j] = (v2f){A[j] + B[j], A[j] - B[j]};
                }
            } else {
                const bool rok = (unsigned)gr < IMG;
                const float* r1 = p1 + gr * IMG;
                const float* r2 = p2 + gr * IMG;
#pragma unroll
                for (int e = 0; e < 20; ++e) {
                    int gc = gc0 + e;
                    bool ok = rok && ((unsigned)gc < IMG);
                    float a = ok ? r1[gc] : 0.0f;
                    float b = ok ? r2[gc] : 0.0f;
                    v[e] = (v2f){a + b, a - b};
                }
            }
        }
        // mu channel
        v2f m[8];
#pragma unroll
        for (int j = 0; j < 8; ++j) m[j] = (v2f){0.f, 0.f};
#pragma unroll
        for (int k = 0; k < 11; ++k) {
            const v2f wv = {gw[k], gw[k]};
#pragma unroll
            for (int j = 0; j < 8; ++j)
                m[j] = __builtin_elementwise_fma(v[j + k], wv, m[j]);
        }
#pragma unroll
        for (int j = 0; j < 8; ++j) sh2[0][hc0 + j][hr] = m[j];
        // square window in place, then x channel
#pragma unroll
        for (int e = 0; e < 18; ++e) v[e] *= v[e];
        v2f x[8];
#pragma unroll
        for (int j = 0; j < 8; ++j) x[j] = (v2f){0.f, 0.f};
#pragma unroll
        for (int k = 0; k < 11; ++k) {
            const v2f wv = {gw[k], gw[k]};
#pragma unroll
            for (int j = 0; j < 8; ++j)
                x[j] = __builtin_elementwise_fma(v[j + k], wv, x[j]);
        }
#pragma unroll
        for (int j = 0; j < 8; ++j) sh2[1][hc0 + j][hr] = x[j];
    }
    __syncthreads();

    // ================= v-pass: packed fma over (s,d) =================
    const int col = tid & 31;
    const int r0  = (tid >> 5) * 4;
    v2f am[4], ax[4];
    {
        v2f hb[16];
        {
            const float4* s0 = (const float4*)&sh2[0][col][r0];  // 32B aligned
#pragma unroll
            for (int q = 0; q < 8; ++q) ((float4*)hb)[q] = s0[q];
        }
#pragma unroll
        for (int i = 0; i < 4; ++i) {
            v2f s = {0.f, 0.f};
#pragma unroll
            for (int k = 0; k < 11; ++k) {
                const v2f wv = {gw[k], gw[k]};
                s = __builtin_elementwise_fma(wv, hb[i + k], s);
            }
            am[i] = s;
        }
        {
            const float4* s1 = (const float4*)&sh2[1][col][r0];
#pragma unroll
            for (int q = 0; q < 8; ++q) ((float4*)hb)[q] = s1[q];
        }
#pragma unroll
        for (int i = 0; i < 4; ++i) {
            v2f s = {0.f, 0.f};
#pragma unroll
            for (int k = 0; k < 11; ++k) {
                const v2f wv = {gw[k], gw[k]};
                s = __builtin_elementwise_fma(wv, hb[i + k], s);
            }
            ax[i] = s;
        }
    }

    // ---- SSIM from (s,d) algebra ----
    const float C1 = 1.0e-4f, C2 = 9.0e-4f;
    float local = 0.f;
#pragma unroll
    for (int i = 0; i < 4; ++i) {
        v2f mu = am[i];
        v2f mu2 = mu * mu;                        // pk_mul: (ms^2, md^2)
        float sum2 = 0.5f  * (mu2[0] + mu2[1]);   // mu1^2 + mu2^2
        float m12  = 0.25f * (mu2[0] - mu2[1]);   // mu1 * mu2
        v2f xx = ax[i];
        float xsum = 0.5f  * (xx[0] + xx[1]);     // x11 + x22
        float x12  = 0.25f * (xx[0] - xx[1]);
        float sg12  = x12 - m12;
        float sgsum = xsum - sum2;                // sigma1_sq + sigma2_sq
        float num = (2.f * m12 + C1) * (2.f * sg12 + C2);
        float den = (sum2 + C1) * (sgsum + C2);
        local = fmaf(num, __builtin_amdgcn_rcpf(den), local);
    }

#pragma unroll
    for (int off = 32; off > 0; off >>= 1)
        local += __shfl_down(local, off, 64);
    if ((tid & 63) == 0) s_part[tid >> 6] = local;
    __syncthreads();
    if (tid == 0) {
        int bidx = (blockIdx.z * gridDim.y + blockIdx.y) * gridDim.x + blockIdx.x;
        partials[bidx] = s_part[0] + s_part[1] + s_part[2] + s_part[3];
    }
}

__global__ __launch_bounds__(256) void ssim_final_kernel(
    const float* __restrict__ partials, float* __restrict__ out)
{
    __shared__ double sp[4];
    double acc = 0.0;
    for (int i = threadIdx.x; i < NBLOCKS; i += 256)
        acc += (double)partials[i];
#pragma unroll
    for (int off = 32; off > 0; off >>= 1)
        acc += __shfl_down(acc, off, 64);
    if ((threadIdx.x & 63) == 0) sp[threadIdx.x >> 6] = acc;
    __syncthreads();
    if (threadIdx.x == 0) {
        double total = sp[0] + sp[1] + sp[2] + sp[3];
        out[0] = (float)(1.0 - total / (double)((size_t)NIMG * IMG * IMG));
    }
}

extern "C" void kernel_launch(void* const* d_in, const int* in_sizes, int n_in,
                              void* d_out, int out_size, void* d_ws, size_t ws_size,
                              hipStream_t stream) {
    const float* img1 = (const float*)d_in[0];
    const float* img2 = (const float*)d_in[1];
    float* out = (float*)d_out;
    float* partials = (float*)d_ws;   // NBLOCKS floats, fully rewritten each call

    dim3 grid(TILES, TILES, NIMG);
    ssim_tile_kernel<<<grid, dim3(256), 0, stream>>>(img1, img2, partials);
    ssim_final_kernel<<<1, dim3(256), 0, stream>>>(partials, out);
}

// Round 7
// 156.995 us; speedup vs baseline: 1.4714x; 1.4714x over previous
//
#include <hip/hip_runtime.h>

// SSIM loss — fused separable-conv tile kernel, v7.
// vs v6 (regression): direct-global h-pass was lane->row = uncoalesced.
// vs v5: SWAP PASS ORDER. V-conv first, straight from global with lane->col
// mapping (coalesced), accumulator-resident; then h-conv from LDS.
// Eliminates the input staging buffer AND one barrier. LDS = single v-conv
// output buffer [2][32][46] v2f = 23.5KB -> 6 blocks/CU (v5 was 39K/4).
// Packed (s,d) v_pk_fma math and 2-channel algebra retained.

typedef float v2f __attribute__((ext_vector_type(2)));

#define IMG   512
#define NIMG  48
#define TW    32
#define TH    32
#define HSTR  46          // col stride in v2f units; row = 368B = 23*16 (b128-aligned)
#define TILES 16
#define NBLOCKS (NIMG * TILES * TILES)  // 12288

// exp(-(k-5)^2/4.5), unnormalized, symmetric.
#define G0 0.0038659204f
#define G1 0.0285655010f
#define G2 0.1353352832f
#define G3 0.4111123050f
#define G4 0.8007374029f
#define G5 1.0f

__global__ __launch_bounds__(256, 6) void ssim_tile_kernel(
    const float* __restrict__ img1, const float* __restrict__ img2,
    float* __restrict__ partials)
{
    __shared__ v2f sh2[2][TH][HSTR];     // [mu|x][row][padded-col] (s,d) pairs, 23552B
    __shared__ float s_part[4];

    const float gw[11] = {G0,G1,G2,G3,G4,G5,G4,G3,G2,G1,G0};

    const int tid = threadIdx.x;
    const int tx0 = blockIdx.x * TW - 5;
    const int ty0 = blockIdx.y * TH - 5;
    const float* __restrict__ p1 = img1 + (size_t)blockIdx.z * (IMG * IMG);
    const float* __restrict__ p2 = img2 + (size_t)blockIdx.z * (IMG * IMG);

    // ============ v-pass: 168 threads = 42 padded cols x 4 row-segs of 8 ======
    // lane -> col (coalesced global); slide 18 input rows, accumulate 8 outputs
    // x 2 packed channels: (s,d) and (s^2,d^2).
    if (tid < 168) {
        const int c   = tid % 42;
        const int seg = tid / 42;
        const int gc  = tx0 + c;
        const int gr0 = ty0 + seg * 8;

        v2f a0[8], a1[8];
#pragma unroll
        for (int r = 0; r < 8; ++r) { a0[r] = (v2f){0.f, 0.f}; a1[r] = (v2f){0.f, 0.f}; }

        const bool interior = (blockIdx.x >= 1) && (blockIdx.x <= TILES - 2) &&
                              (blockIdx.y >= 1) && (blockIdx.y <= TILES - 2);
        if (interior) {
            const float* q1 = p1 + (size_t)gr0 * IMG + gc;
            const float* q2 = p2 + (size_t)gr0 * IMG + gc;
#pragma unroll
            for (int j = 0; j < 18; ++j) {
                float a = q1[j * IMG], b = q2[j * IMG];
                v2f w0 = (v2f){a + b, a - b};
                v2f w1 = w0 * w0;
#pragma unroll
                for (int r = 0; r < 8; ++r) {
                    int k = j - r;
                    if (k >= 0 && k <= 10) {
                        const v2f wv = {gw[k], gw[k]};
                        a0[r] = __builtin_elementwise_fma(w0, wv, a0[r]);
                        a1[r] = __builtin_elementwise_fma(w1, wv, a1[r]);
                    }
                }
            }
        } else {
            const bool cok = (unsigned)gc < IMG;
#pragma unroll
            for (int j = 0; j < 18; ++j) {
                int gr = gr0 + j;
                bool ok = cok && ((unsigned)gr < IMG);
                float a = 0.f, b = 0.f;
                if (ok) {
                    a = p1[(size_t)gr * IMG + gc];
                    b = p2[(size_t)gr * IMG + gc];
                }
                v2f w0 = (v2f){a + b, a - b};
                v2f w1 = w0 * w0;
#pragma unroll
                for (int r = 0; r < 8; ++r) {
                    int k = j - r;
                    if (k >= 0 && k <= 10) {
                        const v2f wv = {gw[k], gw[k]};
                        a0[r] = __builtin_elementwise_fma(w0, wv, a0[r]);
                        a1[r] = __builtin_elementwise_fma(w1, wv, a1[r]);
                    }
                }
            }
        }
#pragma unroll
        for (int r = 0; r < 8; ++r) {
            sh2[0][seg * 8 + r][c] = a0[r];
            sh2[1][seg * 8 + r][c] = a1[r];
        }
    }
    __syncthreads();

    // ============ h-pass: 256 threads = 32 rows x 8 groups of 4 cols ==========
    const int row = tid >> 3;
    const int c0  = (tid & 7) * 4;       // even -> 32B offset -> b128-aligned
    v2f am[4], ax[4];
    {
        v2f hb[14];
        {
            const float4* s0 = (const float4*)&sh2[0][row][c0];
#pragma unroll
            for (int q = 0; q < 7; ++q) ((float4*)hb)[q] = s0[q];
        }
#pragma unroll
        for (int i = 0; i < 4; ++i) {
            v2f s = {0.f, 0.f};
#pragma unroll
            for (int k = 0; k < 11; ++k) {
                const v2f wv = {gw[k], gw[k]};
                s = __builtin_elementwise_fma(wv, hb[i + k], s);
            }
            am[i] = s;
        }
        {
            const float4* s1 = (const float4*)&sh2[1][row][c0];
#pragma unroll
            for (int q = 0; q < 7; ++q) ((float4*)hb)[q] = s1[q];
        }
#pragma unroll
        for (int i = 0; i < 4; ++i) {
            v2f s = {0.f, 0.f};
#pragma unroll
            for (int k = 0; k < 11; ++k) {
                const v2f wv = {gw[k], gw[k]};
                s = __builtin_elementwise_fma(wv, hb[i + k], s);
            }
            ax[i] = s;
        }
    }

    // ---- SSIM from (s,d) algebra ----
    const float C1 = 1.0e-4f, C2 = 9.0e-4f;
    float local = 0.f;
#pragma unroll
    for (int i = 0; i < 4; ++i) {
        v2f mu = am[i];
        v2f mu2 = mu * mu;                        // pk_mul: (ms^2, md^2)
        float sum2 = 0.5f  * (mu2[0] + mu2[1]);   // mu1^2 + mu2^2
        float m12  = 0.25f * (mu2[0] - mu2[1]);   // mu1 * mu2
        v2f xx = ax[i];
        float xsum = 0.5f  * (xx[0] + xx[1]);     // x11 + x22
        float x12  = 0.25f * (xx[0] - xx[1]);
        float sg12  = x12 - m12;
        float sgsum = xsum - sum2;                // sigma1_sq + sigma2_sq
        float num = (2.f * m12 + C1) * (2.f * sg12 + C2);
        float den = (sum2 + C1) * (sgsum + C2);
        local = fmaf(num, __builtin_amdgcn_rcpf(den), local);
    }

#pragma unroll
    for (int off = 32; off > 0; off >>= 1)
        local += __shfl_down(local, off, 64);
    if ((tid & 63) == 0) s_part[tid >> 6] = local;
    __syncthreads();
    if (tid == 0) {
        int bidx = (blockIdx.z * gridDim.y + blockIdx.y) * gridDim.x + blockIdx.x;
        partials[bidx] = s_part[0] + s_part[1] + s_part[2] + s_part[3];
    }
}

__global__ __launch_bounds__(256) void ssim_final_kernel(
    const float* __restrict__ partials, float* __restrict__ out)
{
    __shared__ double sp[4];
    double acc = 0.0;
    for (int i = threadIdx.x; i < NBLOCKS; i += 256)
        acc += (double)partials[i];
#pragma unroll
    for (int off = 32; off > 0; off >>= 1)
        acc += __shfl_down(acc, off, 64);
    if ((threadIdx.x & 63) == 0) sp[threadIdx.x >> 6] = acc;
    __syncthreads();
    if (threadIdx.x == 0) {
        double total = sp[0] + sp[1] + sp[2] + sp[3];
        out[0] = (float)(1.0 - total / (double)((size_t)NIMG * IMG * IMG));
    }
}

extern "C" void kernel_launch(void* const* d_in, const int* in_sizes, int n_in,
                              void* d_out, int out_size, void* d_ws, size_t ws_size,
                              hipStream_t stream) {
    const float* img1 = (const float*)d_in[0];
    const float* img2 = (const float*)d_in[1];
    float* out = (float*)d_out;
    float* partials = (float*)d_ws;   // NBLOCKS floats, fully rewritten each call

    dim3 grid(TILES, TILES, NIMG);
    ssim_tile_kernel<<<grid, dim3(256), 0, stream>>>(img1, img2, partials);
    ssim_final_kernel<<<1, dim3(256), 0, stream>>>(partials, out);
}